// Round 7
// baseline (311.423 us; speedup 1.0000x reference)
//
#include <hip/hip_runtime.h>
#include <math.h>

typedef unsigned long long u64;
typedef unsigned int u32;

#define M_ANCH 360000
#define NCLS 80
#define KTOP 1000
#define CAP 8192
#define NBINS 65536
#define RREP 64          /* R4: RREP=8 -> ~3-4K-deep hot bins = ~40us serialization */
#define CONF_THRESH 0.05f
#define NMS_THRESH 0.6f
#define CTR_CLAMP 32.0f
#define SCALE_CLAMP 4.1351665567423560f  /* log(1000/16) */

#define AS1 __attribute__((address_space(1)))
#define AS3 __attribute__((address_space(3)))

/* ---- workspace layout (bytes): zeroed region first, write-before-read after
   Histogram is u16-packed (2 bins per u32 word): each replica receives
   <= 4*88*16 = 5632 adds total (rep is a function of (tile,w) only), so any
   per-replica bin count < 65535 -> no overflow, and the +1<<16 add for odd
   bins can never carry into the neighboring halfword. */
#define HIST_OFF   0u
#define HIST_BYTES (RREP * NBINS * 2u)            /* 8,388,608 */
#define CNT_OFF    (HIST_OFF + HIST_BYTES)
#define B_OFF      (CNT_OFF + 4u)
#define VW_OFF     (B_OFF + 4u + 8u)              /* 8B aligned */
#define DONE_OFF   (VW_OFF + 128u)                /* 3 done-counters */
#define ZERO_END   (DONE_OFF + 16u)               /* ~8.4 MB zeroed */
#define MERGED_OFF ((ZERO_END + 15u) & ~15u)      /* 65536*4 */
#define BLKSUM_OFF (MERGED_OFF + NBINS * 4u)      /* 64*4 (pad 256) */
#define CAND_OFF   (BLKSUM_OFF + 256u)            /* 8192*8 */
#define SC_OFF     (CAND_OFF + CAP * 8u)          /* M floats */
#define CLS_OFF    (SC_OFF + M_ANCH * 4u)         /* M ints */
#define SSC_OFF    (CLS_OFF + M_ANCH * 4u)        /* 1000 floats */
#define SCLS_OFF   (SSC_OFF + KTOP * 4u)          /* 1000 ints */
#define SUP_OFF    ((SCLS_OFF + KTOP * 4u + 15u) & ~15u)  /* 16000 u64 */

#define NTILES 5625       /* 360000 / 64 anchors per tile */
#define SCORE_GRID 1024   /* 4 blocks/CU (2x20KB LDS), persistent */
#define SUPNMS_GRID 250   /* 64 sup-words per block */

__device__ __forceinline__ u32 fkey(float f) {
    u32 u = __float_as_uint(f);
    return (u & 0x80000000u) ? ~u : (u | 0x80000000u);
}
__device__ __forceinline__ float unfkey(u32 u) {
    u32 f = (u & 0x80000000u) ? (u & 0x7FFFFFFFu) : ~u;
    return __uint_as_float(f);
}

/* K1: persistent double-buffered streaming argmax (R5-proven, UNCHANGED
   except u16-packed hist word addressing).
   R4 lessons baked in: steady-state s_waitcnt vmcnt(8) keeps the previous
   iteration's 3 stores/atomic out of the critical path (first iteration
   must stay vmcnt(5)); RREP=64 keeps hot-bin atomic depth ~5us. */
__global__ __launch_bounds__(256) void k_score(const float* __restrict__ cls_pred,
                                               float* __restrict__ sc_all,
                                               int* __restrict__ cls_all,
                                               u32* __restrict__ hist) {
    __shared__ float4 stage[2][1280];
    const int t = threadIdx.x;
    const int w = t >> 6;          /* wave id 0..3  -> anchors [16w,16w+16) */
    const int l = t & 63;
    const int q = l >> 2;          /* anchor within the wave's 16 */
    const int p = l & 3;           /* class-quarter: chunks [5p,5p+5) */

    int tile = blockIdx.x;
    {   /* prologue: stage first tile into buf0 */
        const float4* gp = (const float4*)cls_pred + (size_t)tile * 1280;
#pragma unroll
        for (int k = 0; k < 5; k++) {
            int f = t + 256 * k;
            __builtin_amdgcn_global_load_lds((AS1 void*)(gp + f),
                                             (AS3 void*)(&stage[0][f]), 16, 0, 0);
        }
    }
    int cur = 0;
    for (; tile < NTILES; tile += SCORE_GRID) {
        int next = tile + SCORE_GRID;
        if (next < NTILES) {
            const float4* gp = (const float4*)cls_pred + (size_t)next * 1280;
#pragma unroll
            for (int k = 0; k < 5; k++) {
                int f = t + 256 * k;
                __builtin_amdgcn_global_load_lds((AS1 void*)(gp + f),
                                                 (AS3 void*)(&stage[cur ^ 1][f]), 16, 0, 0);
            }
            if (tile == (int)blockIdx.x) {
                /* first iter: queue = prefetch(cur)5 + prefetch(next)5 */
                asm volatile("s_waitcnt vmcnt(5)" ::: "memory");
            } else {
                /* steady: queue = prefetch(cur)5, stores(prev)3, prefetch(next)5
                   -> allow newest 8; wait only on prefetch(cur) */
                asm volatile("s_waitcnt vmcnt(8)" ::: "memory");
            }
        } else {
            asm volatile("s_waitcnt vmcnt(0)" ::: "memory");
        }
        __builtin_amdgcn_s_barrier();
        __builtin_amdgcn_sched_barrier(0);

        const float4* av = &stage[cur][(16 * w + q) * 20];
        float mv = -1e30f; int mc = 0;
#pragma unroll
        for (int i = 0; i < 5; i++) {
            int k = 5 * p + ((i + q) % 5);
            float4 v = av[k];
            float lm_ = v.x; int lc_ = 4 * k;
            if (v.y > lm_) { lm_ = v.y; lc_ = 4 * k + 1; }
            if (v.z > lm_) { lm_ = v.z; lc_ = 4 * k + 2; }
            if (v.w > lm_) { lm_ = v.w; lc_ = 4 * k + 3; }
            if (lm_ > mv || (lm_ == mv && lc_ < mc)) { mv = lm_; mc = lc_; }
        }
        u64 key = ((u64)fkey(mv) << 32) | (u64)(~(u32)mc);
        u64 o = __shfl_xor(key, 1); if (o > key) key = o;
        o = __shfl_xor(key, 2);     if (o > key) key = o;
        if (p == 0) {
            int a = tile * 64 + 16 * w + q;
            float lv = unfkey((u32)(key >> 32));
            float sc = 1.0f / (1.0f + expf(-lv));
            sc_all[a] = sc;
            cls_all[a] = (int)(~(u32)key);
            float msk = (sc >= CONF_THRESH) ? sc : -1.0f;
            u32 rep = ((u32)tile * 7u + (u32)w) & (RREP - 1);
            u32 bin = fkey(msk) >> 16;
            /* u16-packed: 2 bins per word; carry impossible (<5632/replica) */
            atomicAdd(&hist[(rep << 15) + (bin >> 1)], 1u << ((bin & 1) << 4));
        }
        __builtin_amdgcn_s_barrier();     /* buf[cur] consumed before reuse */
        __builtin_amdgcn_sched_barrier(0);
        cur ^= 1;
    }
}

/* K2 (fused hsum+boundary). Fence discipline (R2 lesson): one release fence
   by thread 0 only (one wbl2/block), ticket atomic, one acquire fence in
   the winner. u16-unpack on the replica merge (8.4 MB read). */
__global__ __launch_bounds__(1024) void k_hsum_boundary(const u32* __restrict__ hist,
                                                        u32* __restrict__ merged,
                                                        u32* __restrict__ blksum,
                                                        u32* __restrict__ done,
                                                        u32* __restrict__ outB) {
    __shared__ u32 red[1024];
    __shared__ u32 bs[64];
    __shared__ u32 sj, sA;
    __shared__ int sflag;
    int t = threadIdx.x;
    int b = blockIdx.x * 1024 + t;
    int word = b >> 1;
    int sh = (b & 1) << 4;
    u32 s = 0;
#pragma unroll 8
    for (int r = 0; r < RREP; r++) s += (hist[(r << 15) + word] >> sh) & 0xFFFFu;
    merged[b] = s;
    red[t] = s;
    __syncthreads();
    for (int off = 512; off > 0; off >>= 1) {
        if (t < off) red[t] += red[t + off];
        __syncthreads();
    }
    if (t == 0) blksum[blockIdx.x] = red[0];
    __syncthreads();                      /* all stores at L2 */
    if (t == 0) {
        __threadfence();                  /* release: one wbl2 per block */
        sflag = (atomicAdd(done, 1u) == 63u) ? 1 : 0;
    }
    __syncthreads();
    if (!sflag) return;
    if (t == 0) __threadfence();          /* acquire */
    __syncthreads();

    if (t < 64) bs[t] = blksum[t];
    __syncthreads();
    if (t == 0) {
        u32 cum = 0; u32 j = 0; u32 Aj = 0;
        for (int i = 63; i >= 0; i--) {
            if (cum + bs[i] >= KTOP) { j = (u32)i; Aj = cum; break; }
            cum += bs[i];
        }
        sj = j; sA = Aj;
    }
    __syncthreads();
    u32 j = sj, Aj = sA;
    u32 h = merged[j * 1024 + t];
    red[t] = h;
    __syncthreads();
    u32 v = h;
    for (int off = 1; off < 1024; off <<= 1) {
        u32 add = (t + off < 1024) ? red[t + off] : 0u;
        __syncthreads();
        v += add;
        red[t] = v;
        __syncthreads();
    }
    u32 above = (t == 1023) ? 0u : red[t + 1];
    if (Aj + above < KTOP && Aj + above + h >= KTOP) outB[0] = j * 1024 + t;
}

/* K3 (fused compact+select), per-block single fence (89 tickets). */
__global__ __launch_bounds__(1024) void k_compact_select(const float* __restrict__ sc_all,
                                                         const int* __restrict__ cls_all,
                                                         const u32* __restrict__ pB,
                                                         const float* __restrict__ reg_pred,
                                                         const float* __restrict__ anchors,
                                                         u32* __restrict__ counter,
                                                         u64* __restrict__ cand,
                                                         u32* __restrict__ done,
                                                         float* __restrict__ out,
                                                         float* __restrict__ sel_sc,
                                                         int* __restrict__ sel_cls,
                                                         u64* __restrict__ valid_words) {
    __shared__ u64 keys[CAP];
    __shared__ int sflag;
    int t = threadIdx.x;
    int i4 = blockIdx.x * 1024 + t;
    if (i4 < M_ANCH / 4) {
        u32 B = *pB;
        float4 s4 = ((const float4*)sc_all)[i4];
        float se[4] = { s4.x, s4.y, s4.z, s4.w };
#pragma unroll
        for (int e = 0; e < 4; e++) {
            float m = (se[e] >= CONF_THRESH) ? se[e] : -1.0f;
            u32 u = fkey(m);
            if ((u >> 16) >= B) {
                u32 pos = atomicAdd(counter, 1u);
                if (pos < CAP)
                    cand[pos] = ((u64)u << 32) | (u64)(0xFFFFFFFFu - (u32)(4 * i4 + e));
            }
        }
    }
    __syncthreads();                      /* all stores at L2 */
    if (t == 0) {
        __threadfence();                  /* release */
        sflag = (atomicAdd(done, 1u) == gridDim.x - 1) ? 1 : 0;
    }
    __syncthreads();
    if (!sflag) return;
    if (t == 0) __threadfence();          /* acquire */
    __syncthreads();

    u32 n = *counter;
    if (n > CAP) n = CAP;
    u32 P = 1024;
    while (P < n) P <<= 1;
    for (u32 i = t; i < P; i += 1024) keys[i] = (i < n) ? cand[i] : 0ull;
    for (u32 k = 2; k <= P; k <<= 1) {
        for (u32 j = k >> 1; j > 0; j >>= 1) {
            __syncthreads();
            for (u32 i = t; i < P; i += 1024) {
                u32 ixj = i ^ j;
                if (ixj > i) {
                    u64 a = keys[i], bb = keys[ixj];
                    bool desc = ((i & k) == 0);
                    if (desc ? (a < bb) : (a > bb)) { keys[i] = bb; keys[ixj] = a; }
                }
            }
        }
    }
    __syncthreads();
    if (t < KTOP) {
        u64 key = keys[t];
        u32 idx = 0xFFFFFFFFu - (u32)(key & 0xFFFFFFFFull);
        if (idx >= M_ANCH) idx = 0;
        float s = sc_all[idx];
        int cl = cls_all[idx];
        float4 a = ((const float4*)anchors)[idx];
        float4 r = ((const float4*)reg_pred)[idx];
        float ox = fminf(fmaxf(r.x * a.z, -CTR_CLAMP), CTR_CLAMP);
        float oy = fminf(fmaxf(r.y * a.w, -CTR_CLAMP), CTR_CLAMP);
        float cx = a.x + ox, cy = a.y + oy;
        float ww = a.z * expf(fminf(r.z, SCALE_CLAMP));
        float hh = a.w * expf(fminf(r.w, SCALE_CLAMP));
        float4 box;
        box.x = cx - 0.5f * ww;
        box.y = cy - 0.5f * hh;
        box.z = cx + 0.5f * ww;
        box.w = cy + 0.5f * hh;
        ((float4*)out)[t] = box;                 /* boxes: out[0..3999] */
        out[5 * KTOP + t] = (float)cl;           /* classes: out[5000..5999] */
        sel_sc[t] = s;
        sel_cls[t] = cl;
        if (s >= CONF_THRESH) atomicOr(&valid_words[t >> 6], 1ull << (t & 63));
    }
}

/* K4 (fused supmat+nms, per-BLOCK fences — R2's regression was per-THREAD
   fences at 256K scale; R5 proved 64/89-ticket versions cheap, this is 250).
   64 words/block, 16 per wave; diagonal-skip. Winner block (256 thr) runs
   the single-wave greedy NMS; all 4 waves execute the barriers. */
__global__ __launch_bounds__(256) void k_supmat_nms(const float* __restrict__ outb,
                                                    const int* __restrict__ sel_cls,
                                                    u64* __restrict__ sup,
                                                    u32* __restrict__ done,
                                                    const u64* __restrict__ valid_words,
                                                    const float* __restrict__ sel_sc,
                                                    float* __restrict__ out) {
    __shared__ u64 keepA[16];
    __shared__ int sflag;
    int t = threadIdx.x;
    int wid = t >> 6;
    int lane = t & 63;
    int base = blockIdx.x * 64 + wid * 16;    /* 64 words/block, grid 250 */
#pragma unroll 4
    for (int k = 0; k < 16; k++) {
        int g = base + k;                     /* < 16000 */
        int i = g >> 4;
        int w = g & 15;
        if (w * 64 > i) {
            if (lane == 0) sup[g] = 0ull;
            continue;
        }
        int j = w * 64 + lane;
        int jc = (j < KTOP) ? j : (KTOP - 1);
        float4 bi = ((const float4*)outb)[i];
        float4 bj = ((const float4*)outb)[jc];
        int ci = sel_cls[i], cj = sel_cls[jc];
        float ai = (bi.z - bi.x) * (bi.w - bi.y);
        float aj = (bj.z - bj.x) * (bj.w - bj.y);
        float xx1 = fmaxf(bi.x, bj.x), yy1 = fmaxf(bi.y, bj.y);
        float xx2 = fminf(bi.z, bj.z), yy2 = fminf(bi.w, bj.w);
        float iw = fmaxf(1e-28f, xx2 - xx1), ih = fmaxf(1e-28f, yy2 - yy1);
        float inter = iw * ih;
        float iou = inter / (ai + aj - inter + 1e-14f);
        bool pred = (j < i) && (ci == cj) && (iou > NMS_THRESH);
        u64 bal = __ballot((int)pred);
        if (lane == 0) sup[g] = bal;
    }
    __syncthreads();                      /* all stores at L2 */
    if (t == 0) {
        __threadfence();                  /* release: one wbl2 per block */
        sflag = (atomicAdd(done, 1u) == gridDim.x - 1) ? 1 : 0;
    }
    __syncthreads();
    if (!sflag) return;
    if (t == 0) __threadfence();          /* acquire: other blocks' sup */
    __syncthreads();

    if (t < 16) keepA[t] = 0ull;
    __syncthreads();

    for (int b = 0; b < 16; b++) {
        if (wid == 0) {
            int row = b * 64 + lane;
            int rowc = (row < KTOP) ? row : (KTOP - 1);
            const ulonglong2* rp = (const ulonglong2*)(sup + (size_t)rowc * 16);
            ulonglong2 q0 = rp[0], q1 = rp[1], q2 = rp[2], q3 = rp[3];
            ulonglong2 q4 = rp[4], q5 = rp[5], q6 = rp[6], q7 = rp[7];
            u64 d = sup[(size_t)rowc * 16 + b];
            u64 vm = valid_words[b];

            u64 acc = (q0.x & keepA[0])  | (q0.y & keepA[1])
                    | (q1.x & keepA[2])  | (q1.y & keepA[3])
                    | (q2.x & keepA[4])  | (q2.y & keepA[5])
                    | (q3.x & keepA[6])  | (q3.y & keepA[7])
                    | (q4.x & keepA[8])  | (q4.y & keepA[9])
                    | (q5.x & keepA[10]) | (q5.y & keepA[11])
                    | (q6.x & keepA[12]) | (q6.y & keepA[13])
                    | (q7.x & keepA[14]) | (q7.y & keepA[15]);
            u64 premask = __ballot(acc != 0ull);
            u64 eligible = vm & ~premask;

            u32 dlo = (u32)d, dhi = (u32)(d >> 32);
            u64 kb = 0ull;
#pragma unroll
            for (int jj = 0; jj < 64; jj++) {
                u32 djl = __builtin_amdgcn_readlane(dlo, jj);
                u32 djh = __builtin_amdgcn_readlane(dhi, jj);
                u64 dj = ((u64)djh << 32) | (u64)djl;
                bool kj = (((eligible >> jj) & 1ull) != 0ull) && ((dj & kb) == 0ull);
                kb |= ((u64)(kj ? 1u : 0u)) << jj;
            }
            if (lane == 0) keepA[b] = kb;
        }
        __syncthreads();
    }

    for (int tt = t; tt < KTOP; tt += 256) {
        int kb = (int)((keepA[tt >> 6] >> (tt & 63)) & 1ull);
        float s = sel_sc[tt];
        out[4 * KTOP + tt] = kb ? s : 0.0f;   /* scores*keep: out[4000..4999] */
        out[6 * KTOP + tt] = (float)kb;       /* keep:        out[6000..6999] */
    }
}

extern "C" void kernel_launch(void* const* d_in, const int* in_sizes, int n_in,
                              void* d_out, int out_size, void* d_ws, size_t ws_size,
                              hipStream_t stream) {
    const float* cls_pred = (const float*)d_in[0];
    const float* reg_pred = (const float*)d_in[1];
    const float* anchors  = (const float*)d_in[2];
    float* out = (float*)d_out;
    char* ws = (char*)d_ws;

    u32* hist     = (u32*)(ws + HIST_OFF);
    u32* counter  = (u32*)(ws + CNT_OFF);
    u32* pB       = (u32*)(ws + B_OFF);
    u64* vwords   = (u64*)(ws + VW_OFF);
    u32* dones    = (u32*)(ws + DONE_OFF);      /* [0]=hsum [1]=cs [2]=sn */
    u32* merged   = (u32*)(ws + MERGED_OFF);
    u32* blksum   = (u32*)(ws + BLKSUM_OFF);
    u64* cand     = (u64*)(ws + CAND_OFF);
    float* sc_all = (float*)(ws + SC_OFF);
    int* cls_all  = (int*)(ws + CLS_OFF);
    float* sel_sc = (float*)(ws + SSC_OFF);
    int* sel_cls  = (int*)(ws + SCLS_OFF);
    u64* sup      = (u64*)(ws + SUP_OFF);

    hipMemsetAsync(d_ws, 0, ZERO_END, stream);

    k_score<<<SCORE_GRID, 256, 0, stream>>>(cls_pred, sc_all, cls_all, hist);
    k_hsum_boundary<<<NBINS / 1024, 1024, 0, stream>>>(hist, merged, blksum,
                                                       &dones[0], pB);
    int ncs = (M_ANCH / 4 + 1023) / 1024;     /* 88 -> 89 blocks */
    k_compact_select<<<ncs, 1024, 0, stream>>>(sc_all, cls_all, pB, reg_pred,
                                               anchors, counter, cand, &dones[1],
                                               out, sel_sc, sel_cls, vwords);
    k_supmat_nms<<<SUPNMS_GRID, 256, 0, stream>>>(out, sel_cls, sup, &dones[2],
                                                  vwords, sel_sc, out);
}

// Round 8
// 277.511 us; speedup vs baseline: 1.1222x; 1.1222x over previous
//
#include <hip/hip_runtime.h>
#include <math.h>

typedef unsigned long long u64;
typedef unsigned int u32;

#define M_ANCH 360000
#define NCLS 80
#define KTOP 1000
#define CAP 8192
#define NBINS 65536
#define RREP 64          /* R4: RREP=8 -> ~3-4K-deep hot bins = ~40us serialization */
#define CONF_THRESH 0.05f
#define NMS_THRESH 0.6f
#define CTR_CLAMP 32.0f
#define SCALE_CLAMP 4.1351665567423560f  /* log(1000/16) */

#define AS1 __attribute__((address_space(1)))
#define AS3 __attribute__((address_space(3)))

/* ---- workspace layout (bytes): zeroed region first, write-before-read after
   Histogram is u16-packed (2 bins per u32 word): each replica receives
   <= 4*88*16 = 5632 adds total (rep is a function of (tile,w) only), so any
   per-replica bin count < 65535 -> no overflow, and the +1<<16 add for odd
   bins can never carry into the neighboring halfword. */
#define HIST_OFF   0u
#define HIST_BYTES (RREP * NBINS * 2u)            /* 8,388,608 */
#define CNT_OFF    (HIST_OFF + HIST_BYTES)
#define B_OFF      (CNT_OFF + 4u)
#define VW_OFF     (B_OFF + 4u + 8u)              /* 8B aligned */
#define DONE_OFF   (VW_OFF + 128u)                /* 3 done-counters */
#define ZERO_END   (DONE_OFF + 16u)               /* ~8.4 MB zeroed */
#define MERGED_OFF ((ZERO_END + 15u) & ~15u)      /* 65536*4 */
#define BLKSUM_OFF (MERGED_OFF + NBINS * 4u)      /* 64*4 (pad 256) */
#define CAND_OFF   (BLKSUM_OFF + 256u)            /* 8192*8 */
#define SC_OFF     (CAND_OFF + CAP * 8u)          /* M floats */
#define CLS_OFF    (SC_OFF + M_ANCH * 4u)         /* M ints */
#define SSC_OFF    (CLS_OFF + M_ANCH * 4u)        /* 1000 floats */
#define SCLS_OFF   (SSC_OFF + KTOP * 4u)          /* 1000 ints */
#define SUP_OFF    ((SCLS_OFF + KTOP * 4u + 15u) & ~15u)  /* 16000 u64 */

#define NTILES 5625       /* 360000 / 64 anchors per tile */
#define SCORE_GRID 1024   /* 4 blocks/CU (2x20KB LDS), persistent */
#define SUPNMS_GRID 125   /* 128 sup-words per 1024-thread block (exact cover) */

__device__ __forceinline__ u32 fkey(float f) {
    u32 u = __float_as_uint(f);
    return (u & 0x80000000u) ? ~u : (u | 0x80000000u);
}
__device__ __forceinline__ float unfkey(u32 u) {
    u32 f = (u & 0x80000000u) ? (u & 0x7FFFFFFFu) : ~u;
    return __uint_as_float(f);
}

/* K1: persistent double-buffered streaming argmax (R5/R7-proven, UNCHANGED).
   R4 lessons baked in: steady-state s_waitcnt vmcnt(8) keeps the previous
   iteration's 3 stores/atomic out of the critical path (first iteration
   must stay vmcnt(5)); RREP=64 keeps hot-bin atomic depth ~5us. */
__global__ __launch_bounds__(256) void k_score(const float* __restrict__ cls_pred,
                                               float* __restrict__ sc_all,
                                               int* __restrict__ cls_all,
                                               u32* __restrict__ hist) {
    __shared__ float4 stage[2][1280];
    const int t = threadIdx.x;
    const int w = t >> 6;          /* wave id 0..3  -> anchors [16w,16w+16) */
    const int l = t & 63;
    const int q = l >> 2;          /* anchor within the wave's 16 */
    const int p = l & 3;           /* class-quarter: chunks [5p,5p+5) */

    int tile = blockIdx.x;
    {   /* prologue: stage first tile into buf0 */
        const float4* gp = (const float4*)cls_pred + (size_t)tile * 1280;
#pragma unroll
        for (int k = 0; k < 5; k++) {
            int f = t + 256 * k;
            __builtin_amdgcn_global_load_lds((AS1 void*)(gp + f),
                                             (AS3 void*)(&stage[0][f]), 16, 0, 0);
        }
    }
    int cur = 0;
    for (; tile < NTILES; tile += SCORE_GRID) {
        int next = tile + SCORE_GRID;
        if (next < NTILES) {
            const float4* gp = (const float4*)cls_pred + (size_t)next * 1280;
#pragma unroll
            for (int k = 0; k < 5; k++) {
                int f = t + 256 * k;
                __builtin_amdgcn_global_load_lds((AS1 void*)(gp + f),
                                                 (AS3 void*)(&stage[cur ^ 1][f]), 16, 0, 0);
            }
            if (tile == (int)blockIdx.x) {
                /* first iter: queue = prefetch(cur)5 + prefetch(next)5 */
                asm volatile("s_waitcnt vmcnt(5)" ::: "memory");
            } else {
                /* steady: queue = prefetch(cur)5, stores(prev)3, prefetch(next)5
                   -> allow newest 8; wait only on prefetch(cur) */
                asm volatile("s_waitcnt vmcnt(8)" ::: "memory");
            }
        } else {
            asm volatile("s_waitcnt vmcnt(0)" ::: "memory");
        }
        __builtin_amdgcn_s_barrier();
        __builtin_amdgcn_sched_barrier(0);

        const float4* av = &stage[cur][(16 * w + q) * 20];
        float mv = -1e30f; int mc = 0;
#pragma unroll
        for (int i = 0; i < 5; i++) {
            int k = 5 * p + ((i + q) % 5);
            float4 v = av[k];
            float lm_ = v.x; int lc_ = 4 * k;
            if (v.y > lm_) { lm_ = v.y; lc_ = 4 * k + 1; }
            if (v.z > lm_) { lm_ = v.z; lc_ = 4 * k + 2; }
            if (v.w > lm_) { lm_ = v.w; lc_ = 4 * k + 3; }
            if (lm_ > mv || (lm_ == mv && lc_ < mc)) { mv = lm_; mc = lc_; }
        }
        u64 key = ((u64)fkey(mv) << 32) | (u64)(~(u32)mc);
        u64 o = __shfl_xor(key, 1); if (o > key) key = o;
        o = __shfl_xor(key, 2);     if (o > key) key = o;
        if (p == 0) {
            int a = tile * 64 + 16 * w + q;
            float lv = unfkey((u32)(key >> 32));
            float sc = 1.0f / (1.0f + expf(-lv));
            sc_all[a] = sc;
            cls_all[a] = (int)(~(u32)key);
            float msk = (sc >= CONF_THRESH) ? sc : -1.0f;
            u32 rep = ((u32)tile * 7u + (u32)w) & (RREP - 1);
            u32 bin = fkey(msk) >> 16;
            /* u16-packed: 2 bins per word; carry impossible (<5632/replica) */
            atomicAdd(&hist[(rep << 15) + (bin >> 1)], 1u << ((bin & 1) << 4));
        }
        __builtin_amdgcn_s_barrier();     /* buf[cur] consumed before reuse */
        __builtin_amdgcn_sched_barrier(0);
        cur ^= 1;
    }
}

/* K2 (fused hsum+boundary). Fence discipline (R2 lesson): one release fence
   by thread 0 only (one wbl2/block), ticket atomic, one acquire fence in
   the winner. u16-unpack on the replica merge (8.4 MB read). UNCHANGED. */
__global__ __launch_bounds__(1024) void k_hsum_boundary(const u32* __restrict__ hist,
                                                        u32* __restrict__ merged,
                                                        u32* __restrict__ blksum,
                                                        u32* __restrict__ done,
                                                        u32* __restrict__ outB) {
    __shared__ u32 red[1024];
    __shared__ u32 bs[64];
    __shared__ u32 sj, sA;
    __shared__ int sflag;
    int t = threadIdx.x;
    int b = blockIdx.x * 1024 + t;
    int word = b >> 1;
    int sh = (b & 1) << 4;
    u32 s = 0;
#pragma unroll 8
    for (int r = 0; r < RREP; r++) s += (hist[(r << 15) + word] >> sh) & 0xFFFFu;
    merged[b] = s;
    red[t] = s;
    __syncthreads();
    for (int off = 512; off > 0; off >>= 1) {
        if (t < off) red[t] += red[t + off];
        __syncthreads();
    }
    if (t == 0) blksum[blockIdx.x] = red[0];
    __syncthreads();                      /* all stores at L2 */
    if (t == 0) {
        __threadfence();                  /* release: one wbl2 per block */
        sflag = (atomicAdd(done, 1u) == 63u) ? 1 : 0;
    }
    __syncthreads();
    if (!sflag) return;
    if (t == 0) __threadfence();          /* acquire */
    __syncthreads();

    if (t < 64) bs[t] = blksum[t];
    __syncthreads();
    if (t == 0) {
        u32 cum = 0; u32 j = 0; u32 Aj = 0;
        for (int i = 63; i >= 0; i--) {
            if (cum + bs[i] >= KTOP) { j = (u32)i; Aj = cum; break; }
            cum += bs[i];
        }
        sj = j; sA = Aj;
    }
    __syncthreads();
    u32 j = sj, Aj = sA;
    u32 h = merged[j * 1024 + t];
    red[t] = h;
    __syncthreads();
    u32 v = h;
    for (int off = 1; off < 1024; off <<= 1) {
        u32 add = (t + off < 1024) ? red[t + off] : 0u;
        __syncthreads();
        v += add;
        red[t] = v;
        __syncthreads();
    }
    u32 above = (t == 1023) ? 0u : red[t + 1];
    if (Aj + above < KTOP && Aj + above + h >= KTOP) outB[0] = j * 1024 + t;
}

/* K3 (fused compact+select), per-block single fence (89 tickets). UNCHANGED. */
__global__ __launch_bounds__(1024) void k_compact_select(const float* __restrict__ sc_all,
                                                         const int* __restrict__ cls_all,
                                                         const u32* __restrict__ pB,
                                                         const float* __restrict__ reg_pred,
                                                         const float* __restrict__ anchors,
                                                         u32* __restrict__ counter,
                                                         u64* __restrict__ cand,
                                                         u32* __restrict__ done,
                                                         float* __restrict__ out,
                                                         float* __restrict__ sel_sc,
                                                         int* __restrict__ sel_cls,
                                                         u64* __restrict__ valid_words) {
    __shared__ u64 keys[CAP];
    __shared__ int sflag;
    int t = threadIdx.x;
    int i4 = blockIdx.x * 1024 + t;
    if (i4 < M_ANCH / 4) {
        u32 B = *pB;
        float4 s4 = ((const float4*)sc_all)[i4];
        float se[4] = { s4.x, s4.y, s4.z, s4.w };
#pragma unroll
        for (int e = 0; e < 4; e++) {
            float m = (se[e] >= CONF_THRESH) ? se[e] : -1.0f;
            u32 u = fkey(m);
            if ((u >> 16) >= B) {
                u32 pos = atomicAdd(counter, 1u);
                if (pos < CAP)
                    cand[pos] = ((u64)u << 32) | (u64)(0xFFFFFFFFu - (u32)(4 * i4 + e));
            }
        }
    }
    __syncthreads();                      /* all stores at L2 */
    if (t == 0) {
        __threadfence();                  /* release */
        sflag = (atomicAdd(done, 1u) == gridDim.x - 1) ? 1 : 0;
    }
    __syncthreads();
    if (!sflag) return;
    if (t == 0) __threadfence();          /* acquire */
    __syncthreads();

    u32 n = *counter;
    if (n > CAP) n = CAP;
    u32 P = 1024;
    while (P < n) P <<= 1;
    for (u32 i = t; i < P; i += 1024) keys[i] = (i < n) ? cand[i] : 0ull;
    for (u32 k = 2; k <= P; k <<= 1) {
        for (u32 j = k >> 1; j > 0; j >>= 1) {
            __syncthreads();
            for (u32 i = t; i < P; i += 1024) {
                u32 ixj = i ^ j;
                if (ixj > i) {
                    u64 a = keys[i], bb = keys[ixj];
                    bool desc = ((i & k) == 0);
                    if (desc ? (a < bb) : (a > bb)) { keys[i] = bb; keys[ixj] = a; }
                }
            }
        }
    }
    __syncthreads();
    if (t < KTOP) {
        u64 key = keys[t];
        u32 idx = 0xFFFFFFFFu - (u32)(key & 0xFFFFFFFFull);
        if (idx >= M_ANCH) idx = 0;
        float s = sc_all[idx];
        int cl = cls_all[idx];
        float4 a = ((const float4*)anchors)[idx];
        float4 r = ((const float4*)reg_pred)[idx];
        float ox = fminf(fmaxf(r.x * a.z, -CTR_CLAMP), CTR_CLAMP);
        float oy = fminf(fmaxf(r.y * a.w, -CTR_CLAMP), CTR_CLAMP);
        float cx = a.x + ox, cy = a.y + oy;
        float ww = a.z * expf(fminf(r.z, SCALE_CLAMP));
        float hh = a.w * expf(fminf(r.w, SCALE_CLAMP));
        float4 box;
        box.x = cx - 0.5f * ww;
        box.y = cy - 0.5f * hh;
        box.z = cx + 0.5f * ww;
        box.w = cy + 0.5f * hh;
        ((float4*)out)[t] = box;                 /* boxes: out[0..3999] */
        out[5 * KTOP + t] = (float)cl;           /* classes: out[5000..5999] */
        sel_sc[t] = s;
        sel_cls[t] = cl;
        if (s >= CONF_THRESH) atomicOr(&valid_words[t >> 6], 1ull << (t & 63));
    }
}

/* K4 (fused supmat+nms, REDESIGNED winner phase).
   R7 evidence: 73us, VALUBusy 0.86%, occupancy 1.2% -> ~99% stall, nearly
   all of it the single winner block's serial NMS: per b-iteration one wave
   issued 17 HBM-latency loads (sup is cross-XCD-written, post-acquire reads
   come from HBM/IF) with 36 VGPRs of MLP, exposing full latency 16 times.
   New winner: 1024 thr / 16 waves; wave b owns rows [64b,64b+64). ALL 17
   loads/lane issue upfront across 16 waves (one latency exposure, 16x MLP),
   data held in registers; the b=0..15 recurrence then touches only LDS
   keepA + registers (~700cy/step). keepA[j>=b]==0 during step b, so the
   OR over all 16 words reproduces the old premask semantics exactly; the
   intra-block word d is loaded separately (sup[row*16+wid]) to avoid
   dynamic register indexing (rule #20). Supmat phase: 8 words/wave
   (2000 waves, 2x R7 parallelism), exact cover 125*128=16000. */
__global__ __launch_bounds__(1024) void k_supmat_nms(const float* __restrict__ outb,
                                                     const int* __restrict__ sel_cls,
                                                     u64* __restrict__ sup,
                                                     u32* __restrict__ done,
                                                     const u64* __restrict__ valid_words,
                                                     const float* __restrict__ sel_sc,
                                                     float* __restrict__ out) {
    __shared__ u64 keepA[16];
    __shared__ int sflag;
    int t = threadIdx.x;
    int wid = t >> 6;
    int lane = t & 63;
    int base = blockIdx.x * 128 + wid * 8;    /* 128 words/block, grid 125 */
#pragma unroll
    for (int k = 0; k < 8; k++) {
        int g = base + k;                     /* < 16000 exact */
        int i = g >> 4;
        int w = g & 15;
        if (w * 64 > i) {
            if (lane == 0) sup[g] = 0ull;
            continue;
        }
        int j = w * 64 + lane;
        int jc = (j < KTOP) ? j : (KTOP - 1);
        float4 bi = ((const float4*)outb)[i];
        float4 bj = ((const float4*)outb)[jc];
        int ci = sel_cls[i], cj = sel_cls[jc];
        float ai = (bi.z - bi.x) * (bi.w - bi.y);
        float aj = (bj.z - bj.x) * (bj.w - bj.y);
        float xx1 = fmaxf(bi.x, bj.x), yy1 = fmaxf(bi.y, bj.y);
        float xx2 = fminf(bi.z, bj.z), yy2 = fminf(bi.w, bj.w);
        float iw = fmaxf(1e-28f, xx2 - xx1), ih = fmaxf(1e-28f, yy2 - yy1);
        float inter = iw * ih;
        float iou = inter / (ai + aj - inter + 1e-14f);
        bool pred = (j < i) && (ci == cj) && (iou > NMS_THRESH);
        u64 bal = __ballot((int)pred);
        if (lane == 0) sup[g] = bal;
    }
    __syncthreads();                      /* all stores at L2 */
    if (t == 0) {
        __threadfence();                  /* release: one wbl2 per block */
        sflag = (atomicAdd(done, 1u) == SUPNMS_GRID - 1) ? 1 : 0;
    }
    __syncthreads();
    if (!sflag) return;
    if (t == 0) __threadfence();          /* acquire: other blocks' sup */
    __syncthreads();

    /* ---- winner: register-resident wave-pipelined greedy NMS ---- */
    int row = wid * 64 + lane;
    int rowc = (row < KTOP) ? row : (KTOP - 1);
    const ulonglong2* rp = (const ulonglong2*)(sup + (size_t)rowc * 16);
    /* all loads issued here, across all 16 waves -> one latency exposure */
    ulonglong2 q0 = rp[0], q1 = rp[1], q2 = rp[2], q3 = rp[3];
    ulonglong2 q4 = rp[4], q5 = rp[5], q6 = rp[6], q7 = rp[7];
    u64 d  = sup[(size_t)rowc * 16 + wid];   /* intra-block word (idx = own wid) */
    u64 vm = valid_words[wid];

    if (t < 16) keepA[t] = 0ull;
    __syncthreads();

    for (int b = 0; b < 16; b++) {
        if (wid == b) {
            /* keepA[j>=b] are still 0 -> OR over all 16 == premask over j<b */
            u64 acc = (q0.x & keepA[0])  | (q0.y & keepA[1])
                    | (q1.x & keepA[2])  | (q1.y & keepA[3])
                    | (q2.x & keepA[4])  | (q2.y & keepA[5])
                    | (q3.x & keepA[6])  | (q3.y & keepA[7])
                    | (q4.x & keepA[8])  | (q4.y & keepA[9])
                    | (q5.x & keepA[10]) | (q5.y & keepA[11])
                    | (q6.x & keepA[12]) | (q6.y & keepA[13])
                    | (q7.x & keepA[14]) | (q7.y & keepA[15]);
            u64 premask = __ballot(acc != 0ull);
            u64 eligible = vm & ~premask;

            u32 dlo = (u32)d, dhi = (u32)(d >> 32);
            u64 kb = 0ull;
#pragma unroll
            for (int jj = 0; jj < 64; jj++) {
                u32 djl = __builtin_amdgcn_readlane(dlo, jj);
                u32 djh = __builtin_amdgcn_readlane(dhi, jj);
                u64 dj = ((u64)djh << 32) | (u64)djl;
                bool kj = (((eligible >> jj) & 1ull) != 0ull) && ((dj & kb) == 0ull);
                kb |= ((u64)(kj ? 1u : 0u)) << jj;
            }
            if (lane == 0) keepA[b] = kb;
        }
        __syncthreads();
    }

    if (t < KTOP) {
        int kb = (int)((keepA[t >> 6] >> (t & 63)) & 1ull);
        float s = sel_sc[t];
        out[4 * KTOP + t] = kb ? s : 0.0f;   /* scores*keep: out[4000..4999] */
        out[6 * KTOP + t] = (float)kb;       /* keep:        out[6000..6999] */
    }
}

extern "C" void kernel_launch(void* const* d_in, const int* in_sizes, int n_in,
                              void* d_out, int out_size, void* d_ws, size_t ws_size,
                              hipStream_t stream) {
    const float* cls_pred = (const float*)d_in[0];
    const float* reg_pred = (const float*)d_in[1];
    const float* anchors  = (const float*)d_in[2];
    float* out = (float*)d_out;
    char* ws = (char*)d_ws;

    u32* hist     = (u32*)(ws + HIST_OFF);
    u32* counter  = (u32*)(ws + CNT_OFF);
    u32* pB       = (u32*)(ws + B_OFF);
    u64* vwords   = (u64*)(ws + VW_OFF);
    u32* dones    = (u32*)(ws + DONE_OFF);      /* [0]=hsum [1]=cs [2]=sn */
    u32* merged   = (u32*)(ws + MERGED_OFF);
    u32* blksum   = (u32*)(ws + BLKSUM_OFF);
    u64* cand     = (u64*)(ws + CAND_OFF);
    float* sc_all = (float*)(ws + SC_OFF);
    int* cls_all  = (int*)(ws + CLS_OFF);
    float* sel_sc = (float*)(ws + SSC_OFF);
    int* sel_cls  = (int*)(ws + SCLS_OFF);
    u64* sup      = (u64*)(ws + SUP_OFF);

    hipMemsetAsync(d_ws, 0, ZERO_END, stream);

    k_score<<<SCORE_GRID, 256, 0, stream>>>(cls_pred, sc_all, cls_all, hist);
    k_hsum_boundary<<<NBINS / 1024, 1024, 0, stream>>>(hist, merged, blksum,
                                                       &dones[0], pB);
    int ncs = (M_ANCH / 4 + 1023) / 1024;     /* 88 -> 89 blocks */
    k_compact_select<<<ncs, 1024, 0, stream>>>(sc_all, cls_all, pB, reg_pred,
                                               anchors, counter, cand, &dones[1],
                                               out, sel_sc, sel_cls, vwords);
    k_supmat_nms<<<SUPNMS_GRID, 1024, 0, stream>>>(out, sel_cls, sup, &dones[2],
                                                   vwords, sel_sc, out);
}